// Round 1
// baseline (7478.487 us; speedup 1.0000x reference)
//
#include <hip/hip_runtime.h>

#define DEV __device__ __forceinline__

typedef __bf16 bf8 __attribute__((ext_vector_type(8)));
typedef float  f4  __attribute__((ext_vector_type(4)));

DEV unsigned short f2bf(float f){
  unsigned int u = __builtin_bit_cast(unsigned int, f);
  u = u + 0x7fffu + ((u >> 16) & 1u);
  return (unsigned short)(u >> 16);
}
DEV float sigm(float x){ return 1.f/(1.f + __expf(-x)); }
DEV bf8 ldb(const unsigned short* p){ return *reinterpret_cast<const bf8*>(p); }
DEV f4 mfma(bf8 a, bf8 b, f4 c){ return __builtin_amdgcn_mfma_f32_16x16x32_bf16(a, b, c, 0, 0, 0); }

// ---------------- workspace layout (bytes) ----------------
constexpr size_t OFF_WCAT0  = 0;                       // 2 x 1536 x 544 bf16
constexpr size_t SZ_WCAT0   = 2ull*1536*544*2;
constexpr size_t OFF_WCAT1  = OFF_WCAT0 + SZ_WCAT0;    // 1536 x 1536 bf16
constexpr size_t SZ_WCAT1   = 1536ull*1536*2;
constexpr size_t OFF_W1R    = OFF_WCAT1 + SZ_WCAT1;    // 1536 x 1024 bf16
constexpr size_t SZ_W1R     = 1536ull*1024*2;
constexpr size_t OFF_FC1W   = OFF_W1R + SZ_W1R;        // 256 x 1024 bf16
constexpr size_t SZ_FC1W    = 256ull*1024*2;
constexpr size_t OFF_FC2W   = OFF_FC1W + SZ_FC1W;      // 16 x 256 bf16 (padded)
constexpr size_t SZ_FC2W    = 16ull*256*2;
constexpr size_t OFF_BRZ0   = OFF_FC2W + SZ_FC2W;      // 2 x 1024 f32
constexpr size_t OFF_BNIH0  = OFF_BRZ0 + 2*1024*4;     // 2 x 512 f32
constexpr size_t OFF_BNHH0  = OFF_BNIH0 + 2*512*4;     // 2 x 512 f32
constexpr size_t OFF_BRZ1   = OFF_BNHH0 + 2*512*4;     // 1024 f32
constexpr size_t OFF_BNIH1  = OFF_BRZ1 + 1024*4;       // 512 f32
constexpr size_t OFF_BNHH1  = OFF_BNIH1 + 512*4;       // 512 f32
constexpr size_t OFF_BRZ1R  = OFF_BNHH1 + 512*4;       // 1024 f32
constexpr size_t OFF_BNIH1R = OFF_BRZ1R + 1024*4;      // 512 f32
constexpr size_t OFF_BNHH1R = OFF_BNIH1R + 512*4;      // 512 f32
constexpr size_t OFF_SC2    = OFF_BNHH1R + 512*4;      // 256 f32
constexpr size_t OFF_SH2    = OFF_SC2 + 256*4;         // 256 f32
constexpr size_t OFF_FC2B   = OFF_SH2 + 256*4;         // 16 f32
constexpr size_t OFF_Y0     = OFF_FC2B + 16*4;         // 4096 x 28 x 1024 bf16

// ---------------- K0: weight/bias prep ----------------
__global__ void prep_kernel(
  const float* __restrict__ Wih0, const float* __restrict__ Whh0,
  const float* __restrict__ bih0, const float* __restrict__ bhh0,
  const float* __restrict__ Wih0r,const float* __restrict__ Whh0r,
  const float* __restrict__ bih0r,const float* __restrict__ bhh0r,
  const float* __restrict__ Wih1, const float* __restrict__ Whh1,
  const float* __restrict__ bih1, const float* __restrict__ bhh1,
  const float* __restrict__ Wih1r,const float* __restrict__ bih1r,
  const float* __restrict__ bhh1r,
  const float* __restrict__ fc1w, const float* __restrict__ fc1b,
  const float* __restrict__ gma,  const float* __restrict__ bta,
  const float* __restrict__ mean, const float* __restrict__ var,
  const float* __restrict__ fc2w, const float* __restrict__ fc2b,
  unsigned short* __restrict__ wcat0, unsigned short* __restrict__ wcat1,
  unsigned short* __restrict__ w1r,   unsigned short* __restrict__ fc1wb,
  unsigned short* __restrict__ fc2wp,
  float* __restrict__ brz0, float* __restrict__ bnih0, float* __restrict__ bnhh0,
  float* __restrict__ brz1, float* __restrict__ bnih1, float* __restrict__ bnhh1,
  float* __restrict__ brz1r,float* __restrict__ bnih1r,float* __restrict__ bnhh1r,
  float* __restrict__ sc2,  float* __restrict__ sh2,   float* __restrict__ fc2bp)
{
  const int tid = blockIdx.x * blockDim.x + threadIdx.x;
  const int np  = gridDim.x * blockDim.x;
  // fused layer-0 weights: [dir][1536][544], cols 0..31 = W_ih (28 + 4 pad), 32..543 = W_hh
  for (int i = tid; i < 2*1536*544; i += np){
    int d = i / (1536*544); int rem = i - d*(1536*544);
    int n = rem / 544, k = rem - n*544;
    const float* ih = d ? Wih0r : Wih0;
    const float* hh = d ? Whh0r : Whh0;
    float v = (k < 32) ? (k < 28 ? ih[n*28 + k] : 0.f) : hh[n*512 + (k-32)];
    wcat0[i] = f2bf(v);
  }
  // fused layer-1 fwd: [1536][1536], cols 0..1023 = W_ih, 1024..1535 = W_hh
  for (int i = tid; i < 1536*1536; i += np){
    int n = i / 1536, k = i - n*1536;
    float v = (k < 1024) ? Wih1[n*1024 + k] : Whh1[n*512 + (k-1024)];
    wcat1[i] = f2bf(v);
  }
  for (int i = tid; i < 1536*1024; i += np) w1r[i]   = f2bf(Wih1r[i]);
  for (int i = tid; i < 256*1024;  i += np) fc1wb[i] = f2bf(fc1w[i]);
  for (int i = tid; i < 16*256;    i += np){
    int n = i / 256; fc2wp[i] = (n < 10) ? f2bf(fc2w[i]) : (unsigned short)0;
  }
  for (int i = tid; i < 1024; i += np){
    brz0[i]        = bih0[i]  + bhh0[i];
    brz0[1024 + i] = bih0r[i] + bhh0r[i];
    brz1[i]        = bih1[i]  + bhh1[i];
    brz1r[i]       = bih1r[i] + bhh1r[i];
  }
  for (int i = tid; i < 512; i += np){
    bnih0[i]       = bih0[1024 + i];   bnhh0[i]       = bhh0[1024 + i];
    bnih0[512 + i] = bih0r[1024 + i];  bnhh0[512 + i] = bhh0r[1024 + i];
    bnih1[i]       = bih1[1024 + i];   bnhh1[i]       = bhh1[1024 + i];
    bnih1r[i]      = bih1r[1024 + i];  bnhh1r[i]      = bhh1r[1024 + i];
  }
  for (int i = tid; i < 256; i += np){
    float s = gma[i] * rsqrtf(var[i] + 1e-5f);
    sc2[i] = s;
    sh2[i] = (fc1b[i] - mean[i]) * s + bta[i];
  }
  for (int i = tid; i < 16; i += np) fc2bp[i] = (i < 10) ? fc2b[i] : 0.f;
}

// ---------------- K1: layer-0 bidirectional GRU ----------------
// grid 256: blockIdx>>7 = dir, &127 = batch tile (32 rows). 512 threads = 8 waves.
__global__ __launch_bounds__(512, 2) void gru_l0_kernel(
  const float* __restrict__ x, const unsigned short* __restrict__ wcat0,
  const float* __restrict__ brz0, const float* __restrict__ bnih0,
  const float* __restrict__ bnhh0, unsigned short* __restrict__ y0)
{
  constexpr int APS = 552;                 // 544 + 8 pad (bank decorrelation)
  __shared__ unsigned short Ap[32 * APS];  // [x_t (32) | h (512)] bf16
  const int tid  = threadIdx.x;
  const int dir  = blockIdx.x >> 7;
  const int row0 = (blockIdx.x & 127) * 32;
  const unsigned short* W = wcat0 + (size_t)dir * (1536*544);
  const float* brz = brz0  + dir * 1024;
  const float* bni = bnih0 + dir * 512;
  const float* bnh = bnhh0 + dir * 512;

  for (int i = tid; i < 32*APS; i += 512) Ap[i] = 0;   // zeroes x-pad + h0
  __syncthreads();

  const int w = tid >> 6, lane = tid & 63, ln = lane & 15, lq = lane >> 4;
  float hst[2][4][4];
  #pragma unroll
  for (int a = 0; a < 2; ++a)
    #pragma unroll
    for (int b = 0; b < 4; ++b)
      #pragma unroll
      for (int c = 0; c < 4; ++c) hst[a][b][c] = 0.f;

  for (int s = 0; s < 28; ++s){
    const int t = dir ? (27 - s) : s;
    for (int i = tid; i < 32*28; i += 512){
      int r = i / 28, c = i - r*28;
      Ap[r*APS + c] = f2bf(x[(size_t)(row0 + r)*784 + t*28 + c]);
    }
    __syncthreads();

    f4 aR[2][4] = {}, aZ[2][4] = {}, aXN[2][4] = {}, aHN[2][4] = {};
    for (int kt = 0; kt < 17; ++kt){
      const int kc = kt*32 + lq*8;
      bf8 a0 = ldb(&Ap[ln*APS + kc]);
      bf8 a1 = ldb(&Ap[(16 + ln)*APS + kc]);
      const unsigned short* Wk = W + kc;
      #pragma unroll
      for (int nt = 0; nt < 4; ++nt){
        const int rw = w*64 + nt*16 + ln;
        bf8 bR = ldb(&Wk[(size_t)rw*544]);
        bf8 bZ = ldb(&Wk[(size_t)(512 + rw)*544]);
        bf8 bN = ldb(&Wk[(size_t)(1024 + rw)*544]);
        aR[0][nt] = mfma(a0, bR, aR[0][nt]);
        aR[1][nt] = mfma(a1, bR, aR[1][nt]);
        aZ[0][nt] = mfma(a0, bZ, aZ[0][nt]);
        aZ[1][nt] = mfma(a1, bZ, aZ[1][nt]);
        if (kt == 0){
          aXN[0][nt] = mfma(a0, bN, aXN[0][nt]);
          aXN[1][nt] = mfma(a1, bN, aXN[1][nt]);
        } else {
          aHN[0][nt] = mfma(a0, bN, aHN[0][nt]);
          aHN[1][nt] = mfma(a1, bN, aHN[1][nt]);
        }
      }
    }
    __syncthreads();   // all waves done reading Ap before h overwrite

    #pragma unroll
    for (int mt = 0; mt < 2; ++mt){
      #pragma unroll
      for (int nt = 0; nt < 4; ++nt){
        const int c = w*64 + nt*16 + ln;
        const float br = brz[c], bz = brz[512 + c], bi = bni[c], bh = bnh[c];
        #pragma unroll
        for (int e = 0; e < 4; ++e){
          float r = sigm(aR[mt][nt][e] + br);
          float z = sigm(aZ[mt][nt][e] + bz);
          float n = tanhf(aXN[mt][nt][e] + bi + r*(aHN[mt][nt][e] + bh));
          float h = (1.f - z)*n + z*hst[mt][nt][e];
          hst[mt][nt][e] = h;
          const int m = mt*16 + lq*4 + e;
          unsigned short hb = f2bf(h);
          Ap[m*APS + 32 + c] = hb;
          y0[((size_t)(row0 + m)*28 + t)*1024 + dir*512 + c] = hb;
        }
      }
    }
    // no trailing barrier: next x-load writes cols 0..27 (disjoint); the
    // post-x-load barrier publishes h before the next GEMM reads it.
  }
}

// ---------------- K2: layer-1 fwd GRU + 1-step bwd + head ----------------
// grid 128 (batch tiles of 32). 512 threads = 8 waves.
__global__ __launch_bounds__(512, 2) void gru_l1_head_kernel(
  const unsigned short* __restrict__ y0,
  const unsigned short* __restrict__ wcat1,
  const unsigned short* __restrict__ w1r,
  const unsigned short* __restrict__ fc1w,
  const unsigned short* __restrict__ fc2wp,
  const float* __restrict__ brz1,  const float* __restrict__ bnih1,
  const float* __restrict__ bnhh1,
  const float* __restrict__ brz1r, const float* __restrict__ bnih1r,
  const float* __restrict__ bnhh1r,
  const float* __restrict__ sc2,   const float* __restrict__ sh2,
  const float* __restrict__ fc2b,  float* __restrict__ out)
{
  constexpr int APS = 1544;                // 1536 + 8 pad
  __shared__ unsigned short Ap[32 * APS];  // [y0_t (1024) | h1f (512)]
  __shared__ float lg[32 * 16];
  const int tid  = threadIdx.x;
  const int row0 = blockIdx.x * 32;

  for (int i = tid; i < 32*APS; i += 512) Ap[i] = 0;
  __syncthreads();

  const int w = tid >> 6, lane = tid & 63, ln = lane & 15, lq = lane >> 4;
  float hst[2][4][4];
  #pragma unroll
  for (int a = 0; a < 2; ++a)
    #pragma unroll
    for (int b = 0; b < 4; ++b)
      #pragma unroll
      for (int c = 0; c < 4; ++c) hst[a][b][c] = 0.f;

  for (int s = 0; s < 28; ++s){
    for (int i = tid; i < 32*128; i += 512){
      int r = i >> 7, ch = i & 127;
      const uint4 v = *reinterpret_cast<const uint4*>(
          &y0[((size_t)(row0 + r)*28 + s)*1024 + ch*8]);
      *reinterpret_cast<uint4*>(&Ap[r*APS + ch*8]) = v;
    }
    __syncthreads();

    f4 aR[2][4] = {}, aZ[2][4] = {}, aXN[2][4] = {}, aHN[2][4] = {};
    for (int kt = 0; kt < 48; ++kt){
      const int kc = kt*32 + lq*8;
      bf8 a0 = ldb(&Ap[ln*APS + kc]);
      bf8 a1 = ldb(&Ap[(16 + ln)*APS + kc]);
      const unsigned short* Wk = wcat1 + kc;
      #pragma unroll
      for (int nt = 0; nt < 4; ++nt){
        const int rw = w*64 + nt*16 + ln;
        bf8 bR = ldb(&Wk[(size_t)rw*1536]);
        bf8 bZ = ldb(&Wk[(size_t)(512 + rw)*1536]);
        bf8 bN = ldb(&Wk[(size_t)(1024 + rw)*1536]);
        aR[0][nt] = mfma(a0, bR, aR[0][nt]);
        aR[1][nt] = mfma(a1, bR, aR[1][nt]);
        aZ[0][nt] = mfma(a0, bZ, aZ[0][nt]);
        aZ[1][nt] = mfma(a1, bZ, aZ[1][nt]);
        if (kt < 32){
          aXN[0][nt] = mfma(a0, bN, aXN[0][nt]);
          aXN[1][nt] = mfma(a1, bN, aXN[1][nt]);
        } else {
          aHN[0][nt] = mfma(a0, bN, aHN[0][nt]);
          aHN[1][nt] = mfma(a1, bN, aHN[1][nt]);
        }
      }
    }
    __syncthreads();

    #pragma unroll
    for (int mt = 0; mt < 2; ++mt){
      #pragma unroll
      for (int nt = 0; nt < 4; ++nt){
        const int c = w*64 + nt*16 + ln;
        const float br = brz1[c], bz = brz1[512 + c], bi = bnih1[c], bh = bnhh1[c];
        #pragma unroll
        for (int e = 0; e < 4; ++e){
          float r = sigm(aR[mt][nt][e] + br);
          float z = sigm(aZ[mt][nt][e] + bz);
          float n = tanhf(aXN[mt][nt][e] + bi + r*(aHN[mt][nt][e] + bh));
          float h = (1.f - z)*n + z*hst[mt][nt][e];
          hst[mt][nt][e] = h;
          const int m = mt*16 + lq*4 + e;
          Ap[m*APS + 1024 + c] = f2bf(h);
        }
      }
    }
    // next y0 load hits cols 0..1023 (disjoint from h cols); barrier after it.
  }

  // ---- layer-1 backward, single step from h=0, consuming y0[:,27,:] (cols 0..1023)
  {
    f4 aR[2][4] = {}, aZ[2][4] = {}, aXN[2][4] = {};
    for (int kt = 0; kt < 32; ++kt){
      const int kc = kt*32 + lq*8;
      bf8 a0 = ldb(&Ap[ln*APS + kc]);
      bf8 a1 = ldb(&Ap[(16 + ln)*APS + kc]);
      const unsigned short* Wk = w1r + kc;
      #pragma unroll
      for (int nt = 0; nt < 4; ++nt){
        const int rw = w*64 + nt*16 + ln;
        bf8 bR = ldb(&Wk[(size_t)rw*1024]);
        bf8 bZ = ldb(&Wk[(size_t)(512 + rw)*1024]);
        bf8 bN = ldb(&Wk[(size_t)(1024 + rw)*1024]);
        aR[0][nt] = mfma(a0, bR, aR[0][nt]);
        aR[1][nt] = mfma(a1, bR, aR[1][nt]);
        aZ[0][nt] = mfma(a0, bZ, aZ[0][nt]);
        aZ[1][nt] = mfma(a1, bZ, aZ[1][nt]);
        aXN[0][nt] = mfma(a0, bN, aXN[0][nt]);
        aXN[1][nt] = mfma(a1, bN, aXN[1][nt]);
      }
    }
    __syncthreads();
    #pragma unroll
    for (int mt = 0; mt < 2; ++mt){
      #pragma unroll
      for (int nt = 0; nt < 4; ++nt){
        const int c = w*64 + nt*16 + ln;
        const float br = brz1r[c], bz = brz1r[512 + c], bi = bnih1r[c], bh = bnhh1r[c];
        #pragma unroll
        for (int e = 0; e < 4; ++e){
          float r = sigm(aR[mt][nt][e] + br);
          float z = sigm(aZ[mt][nt][e] + bz);
          float n = tanhf(aXN[mt][nt][e] + bi + r*bh);   // gh = b_hh (h=0)
          float h = (1.f - z)*n;                         // + z*0
          const int m = mt*16 + lq*4 + e;
          Ap[m*APS + c] = f2bf(h);                       // h1b -> cols 0..511
        }
      }
    }
    __syncthreads();
  }

  // ---- head: z1 = last @ fc1^T, bn+relu; last[k<512]=Ap[1024+k], last[k>=512]=Ap[k-512]
  {
    f4 acc[2][2] = {};
    for (int kt = 0; kt < 32; ++kt){
      const int pcol = (kt < 16 ? 1024 + kt*32 : (kt - 16)*32) + lq*8;
      bf8 a0 = ldb(&Ap[ln*APS + pcol]);
      bf8 a1 = ldb(&Ap[(16 + ln)*APS + pcol]);
      #pragma unroll
      for (int nt = 0; nt < 2; ++nt){
        const int rw = w*32 + nt*16 + ln;
        bf8 b = ldb(&fc1w[(size_t)rw*1024 + kt*32 + lq*8]);
        acc[0][nt] = mfma(a0, b, acc[0][nt]);
        acc[1][nt] = mfma(a1, b, acc[1][nt]);
      }
    }
    #pragma unroll
    for (int nt = 0; nt < 2; ++nt){
      const int col = w*32 + nt*16 + ln;
      const float sc = sc2[col], sh = sh2[col];
      #pragma unroll
      for (int mt = 0; mt < 2; ++mt){
        #pragma unroll
        for (int e = 0; e < 4; ++e){
          float v = fmaxf(acc[mt][nt][e]*sc + sh, 0.f);
          const int m = mt*16 + lq*4 + e;
          Ap[m*APS + 512 + col] = f2bf(v);               // 'a' -> cols 512..767
        }
      }
    }
    __syncthreads();
  }

  // ---- logits (wave 0) + log_softmax
  if (w == 0){
    f4 acc[2] = {};
    for (int kt = 0; kt < 8; ++kt){
      const int kc = kt*32 + lq*8;
      bf8 a0 = ldb(&Ap[ln*APS + 512 + kc]);
      bf8 a1 = ldb(&Ap[(16 + ln)*APS + 512 + kc]);
      bf8 b  = ldb(&fc2wp[ln*256 + kc]);
      acc[0] = mfma(a0, b, acc[0]);
      acc[1] = mfma(a1, b, acc[1]);
    }
    const float bb = fc2b[ln];
    #pragma unroll
    for (int mt = 0; mt < 2; ++mt)
      #pragma unroll
      for (int e = 0; e < 4; ++e)
        lg[(mt*16 + lq*4 + e)*16 + ln] = acc[mt][e] + bb;
  }
  __syncthreads();
  if (tid < 32){
    const int r = tid;
    float mx = -1e30f;
    for (int c = 0; c < 10; ++c) mx = fmaxf(mx, lg[r*16 + c]);
    float sum = 0.f;
    for (int c = 0; c < 10; ++c) sum += __expf(lg[r*16 + c] - mx);
    const float lse = mx + logf(sum);
    for (int c = 0; c < 10; ++c)
      out[(size_t)(row0 + r)*10 + c] = lg[r*16 + c] - lse;
  }
}

// ---------------- launch ----------------
extern "C" void kernel_launch(void* const* d_in, const int* in_sizes, int n_in,
                              void* d_out, int out_size, void* d_ws, size_t ws_size,
                              hipStream_t stream)
{
  (void)in_sizes; (void)n_in; (void)out_size; (void)ws_size;
  char* ws = (char*)d_ws;
  auto US = [&](size_t off){ return (unsigned short*)(ws + off); };
  auto FP = [&](size_t off){ return (float*)(ws + off); };

  const float* x      = (const float*)d_in[0];
  const float* Wih0   = (const float*)d_in[1];
  const float* Whh0   = (const float*)d_in[2];
  const float* bih0   = (const float*)d_in[3];
  const float* bhh0   = (const float*)d_in[4];
  const float* Wih0r  = (const float*)d_in[5];
  const float* Whh0r  = (const float*)d_in[6];
  const float* bih0r  = (const float*)d_in[7];
  const float* bhh0r  = (const float*)d_in[8];
  const float* Wih1   = (const float*)d_in[9];
  const float* Whh1   = (const float*)d_in[10];
  const float* bih1   = (const float*)d_in[11];
  const float* bhh1   = (const float*)d_in[12];
  const float* Wih1r  = (const float*)d_in[13];
  // d_in[14] (W_hh_l1r) unused: backward layer-1 runs exactly one step from h=0.
  const float* bih1r  = (const float*)d_in[15];
  const float* bhh1r  = (const float*)d_in[16];
  const float* fc1w   = (const float*)d_in[17];
  const float* fc1b   = (const float*)d_in[18];
  const float* gma    = (const float*)d_in[19];
  const float* bta    = (const float*)d_in[20];
  const float* mean   = (const float*)d_in[21];
  const float* var    = (const float*)d_in[22];
  const float* fc2w   = (const float*)d_in[23];
  const float* fc2b   = (const float*)d_in[24];

  prep_kernel<<<512, 256, 0, stream>>>(
    Wih0, Whh0, bih0, bhh0, Wih0r, Whh0r, bih0r, bhh0r,
    Wih1, Whh1, bih1, bhh1, Wih1r, bih1r, bhh1r,
    fc1w, fc1b, gma, bta, mean, var, fc2w, fc2b,
    US(OFF_WCAT0), US(OFF_WCAT1), US(OFF_W1R), US(OFF_FC1W), US(OFF_FC2W),
    FP(OFF_BRZ0), FP(OFF_BNIH0), FP(OFF_BNHH0),
    FP(OFF_BRZ1), FP(OFF_BNIH1), FP(OFF_BNHH1),
    FP(OFF_BRZ1R), FP(OFF_BNIH1R), FP(OFF_BNHH1R),
    FP(OFF_SC2), FP(OFF_SH2), FP(OFF_FC2B));

  gru_l0_kernel<<<256, 512, 0, stream>>>(
    x, US(OFF_WCAT0), FP(OFF_BRZ0), FP(OFF_BNIH0), FP(OFF_BNHH0), US(OFF_Y0));

  gru_l1_head_kernel<<<128, 512, 0, stream>>>(
    US(OFF_Y0), US(OFF_WCAT1), US(OFF_W1R), US(OFF_FC1W), US(OFF_FC2W),
    FP(OFF_BRZ1), FP(OFF_BNIH1), FP(OFF_BNHH1),
    FP(OFF_BRZ1R), FP(OFF_BNIH1R), FP(OFF_BNHH1R),
    FP(OFF_SC2), FP(OFF_SH2), FP(OFF_FC2B), (float*)d_out);
}

// Round 3
// 3528.936 us; speedup vs baseline: 2.1192x; 2.1192x over previous
//
#include <hip/hip_runtime.h>

#define DEV __device__ __forceinline__
typedef unsigned short us;
typedef __bf16 bf8 __attribute__((ext_vector_type(8)));
typedef float  f4  __attribute__((ext_vector_type(4)));

DEV us f2bf(float f){
  unsigned int u = __builtin_bit_cast(unsigned int, f);
  u = u + 0x7fffu + ((u >> 16) & 1u);
  return (us)(u >> 16);
}
DEV float sigm(float x){ return 1.f/(1.f + __expf(-x)); }
DEV bf8 ldb(const us* p){ return *reinterpret_cast<const bf8*>(p); }
DEV f4 mfma(bf8 a, bf8 b, f4 c){ return __builtin_amdgcn_mfma_f32_16x16x32_bf16(a, b, c, 0, 0, 0); }

// ---------------- workspace layout (bytes) — total ~171 MB, safe vs ~256 MB ws
constexpr size_t OFF_WCAT0  = 0;                            // [2][1536][544] bf16
constexpr size_t OFF_WCAT1  = OFF_WCAT0 + 2ull*1536*544*2;  // [1536][1536] bf16
constexpr size_t OFF_W1R    = OFF_WCAT1 + 1536ull*1536*2;   // [1536][1024] bf16
constexpr size_t OFF_FC1W   = OFF_W1R   + 1536ull*1024*2;   // [256][1024] bf16
constexpr size_t OFF_FC2W   = OFF_FC1W  + 256ull*1024*2;    // [16][256] bf16
constexpr size_t OFF_BRZ0   = OFF_FC2W  + 16ull*256*2;      // [2][1024] f32
constexpr size_t OFF_BNIH0  = OFF_BRZ0  + 2*1024*4;         // [2][512]
constexpr size_t OFF_BNHH0  = OFF_BNIH0 + 2*512*4;          // [2][512]
constexpr size_t OFF_BRZ1   = OFF_BNHH0 + 2*512*4;          // [1024]
constexpr size_t OFF_BNIH1  = OFF_BRZ1  + 1024*4;           // [512]
constexpr size_t OFF_BNHH1  = OFF_BNIH1 + 512*4;            // [512]
constexpr size_t OFF_BRZ1R  = OFF_BNHH1 + 512*4;            // [1024]
constexpr size_t OFF_BNIH1R = OFF_BRZ1R + 1024*4;           // [512]
constexpr size_t OFF_BNHH1R = OFF_BNIH1R+ 512*4;            // [512]
constexpr size_t OFF_SC2    = OFF_BNHH1R+ 512*4;            // [256]
constexpr size_t OFF_SH2    = OFF_SC2   + 256*4;            // [256]
constexpr size_t OFF_FC2B   = OFF_SH2   + 256*4;            // [16]
constexpr size_t OFF_Y0B    = OFF_FC2B  + 64;               // [4096][28][512] bf16 (backward half only)
constexpr size_t OFF_H0BF   = OFF_Y0B   + 4096ull*28*512*2; // [2pp][4096][512] bf16
constexpr size_t OFF_H0F32  = OFF_H0BF  + 2ull*4096*512*2;  // [4096][512] f32
constexpr size_t OFF_H1BF   = OFF_H0F32 + 4096ull*512*4;    // [2pp][4096][512] bf16
constexpr size_t OFF_H1F32  = OFF_H1BF  + 2ull*4096*512*2;  // [4096][512] f32
constexpr size_t OFF_H1BBF  = OFF_H1F32 + 4096ull*512*4;    // [4096][512] bf16

constexpr long PP = 4096ll*512;   // elems per ping-pong buffer (one direction)

// ---------------- K0: weight/bias prep ----------------
__global__ void prep_kernel(
  const float* __restrict__ Wih0, const float* __restrict__ Whh0,
  const float* __restrict__ bih0, const float* __restrict__ bhh0,
  const float* __restrict__ Wih0r,const float* __restrict__ Whh0r,
  const float* __restrict__ bih0r,const float* __restrict__ bhh0r,
  const float* __restrict__ Wih1, const float* __restrict__ Whh1,
  const float* __restrict__ bih1, const float* __restrict__ bhh1,
  const float* __restrict__ Wih1r,const float* __restrict__ bih1r,
  const float* __restrict__ bhh1r,
  const float* __restrict__ fc1w, const float* __restrict__ fc1b,
  const float* __restrict__ gma,  const float* __restrict__ bta,
  const float* __restrict__ mean, const float* __restrict__ var,
  const float* __restrict__ fc2w, const float* __restrict__ fc2b,
  us* __restrict__ wcat0, us* __restrict__ wcat1, us* __restrict__ w1r,
  us* __restrict__ fc1wb, us* __restrict__ fc2wp,
  float* __restrict__ brz0, float* __restrict__ bnih0, float* __restrict__ bnhh0,
  float* __restrict__ brz1, float* __restrict__ bnih1, float* __restrict__ bnhh1,
  float* __restrict__ brz1r,float* __restrict__ bnih1r,float* __restrict__ bnhh1r,
  float* __restrict__ sc2,  float* __restrict__ sh2,   float* __restrict__ fc2bp)
{
  const int tid = blockIdx.x * blockDim.x + threadIdx.x;
  const int np  = gridDim.x * blockDim.x;
  // layer-0 fused weights: [dir][1536][544], cols 0..31 = W_ih (28+4 pad), 32..543 = W_hh
  for (int i = tid; i < 2*1536*544; i += np){
    int d = i / (1536*544); int rem = i - d*(1536*544);
    int n = rem / 544, k = rem - n*544;
    const float* ih = d ? Wih0r : Wih0;
    const float* hh = d ? Whh0r : Whh0;
    float v = (k < 32) ? (k < 28 ? ih[n*28 + k] : 0.f) : hh[n*512 + (k-32)];
    wcat0[i] = f2bf(v);
  }
  // layer-1 fwd fused: [1536][1536], cols 0..1023 = W_ih (y0f|y0b), 1024..1535 = W_hh
  for (int i = tid; i < 1536*1536; i += np){
    int n = i / 1536, k = i - n*1536;
    float v = (k < 1024) ? Wih1[n*1024 + k] : Whh1[n*512 + (k-1024)];
    wcat1[i] = f2bf(v);
  }
  for (int i = tid; i < 1536*1024; i += np) w1r[i]   = f2bf(Wih1r[i]);
  for (int i = tid; i < 256*1024;  i += np) fc1wb[i] = f2bf(fc1w[i]);
  for (int i = tid; i < 16*256;    i += np){
    int n = i / 256; fc2wp[i] = (n < 10) ? f2bf(fc2w[i]) : (us)0;
  }
  for (int i = tid; i < 1024; i += np){
    brz0[i]        = bih0[i]  + bhh0[i];
    brz0[1024 + i] = bih0r[i] + bhh0r[i];
    brz1[i]        = bih1[i]  + bhh1[i];
    brz1r[i]       = bih1r[i] + bhh1r[i];
  }
  for (int i = tid; i < 512; i += np){
    bnih0[i]       = bih0[1024 + i];   bnhh0[i]       = bhh0[1024 + i];
    bnih0[512 + i] = bih0r[1024 + i];  bnhh0[512 + i] = bhh0r[1024 + i];
    bnih1[i]       = bih1[1024 + i];   bnhh1[i]       = bhh1[1024 + i];
    bnih1r[i]      = bih1r[1024 + i];  bnhh1r[i]      = bhh1r[1024 + i];
  }
  for (int i = tid; i < 256; i += np){
    float s = gma[i] * rsqrtf(var[i] + 1e-5f);
    sc2[i] = s;
    sh2[i] = (fc1b[i] - mean[i]) * s + bta[i];
  }
  for (int i = tid; i < 16; i += np) fc2bp[i] = (i < 10) ? fc2b[i] : 0.f;
}

// ---------------- generic GRU step ----------------
// One recurrent step as a 2D-tiled GEMM + gate epilogue.
// grid 256: nm = bid&31 (M tile of 128), hcb = bid>>5 (64 h-cols).
// A = [seg0 (K0) | seg1 (K1) | h (rest)], K = nk*32. seg0 is fp32-x if xf32.
// W: [1536][Kw], gate g rows at g*512. XN accumulates chunks < kxn (gx_n),
// spilled to LDS at the boundary; HN accumulates the rest (gh_n).
__global__ __launch_bounds__(512, 4) void gru_step_kernel(
  const float* __restrict__ xf32, long xstride,
  const us* __restrict__ src0, long s0stride, int K0,
  const us* __restrict__ src1, long s1stride, int K1,
  const us* __restrict__ hIn, float* __restrict__ hF, us* __restrict__ hOut,
  us* __restrict__ y, long ystride,
  const us* __restrict__ W, int Kw, int nk, int kxn, int first,
  const float* __restrict__ brz, const float* __restrict__ bni,
  const float* __restrict__ bnh)
{
  __shared__ us As[2*128*40];      // A chunk [128][32] padded to 40, double-buffered
  __shared__ f4 xnSp[512*4];       // XN spill: 16 f32/thread

  const int tid = threadIdx.x, bid = blockIdx.x;
  const int nm = bid & 31, hcb = bid >> 5;
  const size_t Mbase = (size_t)nm * 128;
  const int hcBase = hcb * 64;
  const int K01 = K0 + K1;

  const int w = tid >> 6, lane = tid & 63, ln = lane & 15, lq = lane >> 4;
  const int wm = w >> 2, wn = w & 3;          // wave tile: 64 M x 16 hc
  const int srow = tid >> 2, sgrp = tid & 3;  // staging: row, 8-col group

  const us* pB0 = W + (size_t)(       hcBase + wn*16 + ln) * Kw;
  const us* pB1 = W + (size_t)( 512 + hcBase + wn*16 + ln) * Kw;
  const us* pB2 = W + (size_t)(1024 + hcBase + wn*16 + ln) * Kw;

  // stage chunk 0
  if (xf32){
    const float* xr = xf32 + (Mbase + srow)*xstride;
    us t8[8];
    #pragma unroll
    for (int j = 0; j < 8; ++j){
      int cc = sgrp*8 + j;
      t8[j] = (cc < 28) ? f2bf(xr[cc]) : (us)0;
    }
    *reinterpret_cast<uint4*>(&As[srow*40 + sgrp*8]) = *reinterpret_cast<uint4*>(t8);
  } else {
    *reinterpret_cast<uint4*>(&As[srow*40 + sgrp*8]) =
      *reinterpret_cast<const uint4*>(src0 + (Mbase + srow)*s0stride + sgrp*8);
  }
  __syncthreads();

  f4 accR[4] = {}, accZ[4] = {}, accN[4] = {};
  bf8 bR = ldb(pB0 + lq*8), bZ = ldb(pB1 + lq*8), bN = ldb(pB2 + lq*8);

  for (int kt = 0; kt < nk; ++kt){
    const int buf = (kt & 1) * 5120;
    const bool more = (kt + 1) < nk;
    bf8 bR2, bZ2, bN2; uint4 nv;
    if (more){
      const int kc2 = (kt + 1) * 32;
      bR2 = ldb(pB0 + kc2 + lq*8);
      bZ2 = ldb(pB1 + kc2 + lq*8);
      bN2 = ldb(pB2 + kc2 + lq*8);
      const int col = kc2 + sgrp*8;
      const size_t mrow = Mbase + srow;
      if (col < K0)
        nv = *reinterpret_cast<const uint4*>(src0 + mrow*s0stride + col);
      else if (col < K01)
        nv = *reinterpret_cast<const uint4*>(src1 + mrow*s1stride + (col - K0));
      else if (!first)
        nv = *reinterpret_cast<const uint4*>(hIn + mrow*512 + (col - K01));
      else
        nv = uint4{0,0,0,0};
    }
    bf8 a0 = ldb(&As[buf + (wm*64 +  0 + ln)*40 + lq*8]);
    bf8 a1 = ldb(&As[buf + (wm*64 + 16 + ln)*40 + lq*8]);
    bf8 a2 = ldb(&As[buf + (wm*64 + 32 + ln)*40 + lq*8]);
    bf8 a3 = ldb(&As[buf + (wm*64 + 48 + ln)*40 + lq*8]);
    accR[0] = mfma(a0, bR, accR[0]); accR[1] = mfma(a1, bR, accR[1]);
    accR[2] = mfma(a2, bR, accR[2]); accR[3] = mfma(a3, bR, accR[3]);
    accZ[0] = mfma(a0, bZ, accZ[0]); accZ[1] = mfma(a1, bZ, accZ[1]);
    accZ[2] = mfma(a2, bZ, accZ[2]); accZ[3] = mfma(a3, bZ, accZ[3]);
    accN[0] = mfma(a0, bN, accN[0]); accN[1] = mfma(a1, bN, accN[1]);
    accN[2] = mfma(a2, bN, accN[2]); accN[3] = mfma(a3, bN, accN[3]);
    if (kt == kxn - 1){
      #pragma unroll
      for (int mt = 0; mt < 4; ++mt){ xnSp[tid*4 + mt] = accN[mt]; accN[mt] = f4{0.f,0.f,0.f,0.f}; }
    }
    if (more){
      *reinterpret_cast<uint4*>(&As[(buf ^ 5120) + srow*40 + sgrp*8]) = nv;
      __syncthreads();
      bR = bR2; bZ = bZ2; bN = bN2;
    }
  }

  // ---- gate epilogue ----
  const int c = hcBase + wn*16 + ln;
  const float br = brz[c], bz = brz[512 + c], bi = bni[c], bh = bnh[c];
  #pragma unroll
  for (int mt = 0; mt < 4; ++mt){
    f4 xn = xnSp[tid*4 + mt];
    #pragma unroll
    for (int e = 0; e < 4; ++e){
      const size_t m = Mbase + wm*64 + mt*16 + lq*4 + e;
      float r = sigm(accR[mt][e] + br);
      float z = sigm(accZ[mt][e] + bz);
      float n = tanhf(xn[e] + bi + r*(accN[mt][e] + bh));
      float hprev = first ? 0.f : hF[m*512 + c];
      float h = (1.f - z)*n + z*hprev;
      hF[m*512 + c] = h;
      us hb = f2bf(h);
      hOut[m*512 + c] = hb;
      if (y) y[m*ystride + c] = hb;
    }
  }
}

// ---------------- head: [h1f|h1b] -> fc1 -> bn/relu -> fc2 -> log_softmax ----
__global__ __launch_bounds__(512) void head_kernel(
  const us* __restrict__ h1f, const us* __restrict__ h1b,
  const us* __restrict__ fc1w, const us* __restrict__ fc2wp,
  const float* __restrict__ sc2, const float* __restrict__ sh2,
  const float* __restrict__ fc2b, float* __restrict__ out)
{
  constexpr int APS = 1048;
  __shared__ us As[32 * APS];
  __shared__ us actS[32 * 264];
  __shared__ float lg[32 * 16];
  const int tid = threadIdx.x;
  const size_t row0 = (size_t)blockIdx.x * 32;
  const int w = tid >> 6, lane = tid & 63, ln = lane & 15, lq = lane >> 4;

  for (int i = tid; i < 32*128; i += 512){
    int r = i >> 7, g = i & 127, col = g*8;
    uint4 v = (col < 512)
      ? *reinterpret_cast<const uint4*>(h1f + (row0 + r)*512 + col)
      : *reinterpret_cast<const uint4*>(h1b + (row0 + r)*512 + (col - 512));
    *reinterpret_cast<uint4*>(&As[r*APS + col]) = v;
  }
  __syncthreads();

  {
    f4 acc[2][2] = {};
    for (int kt = 0; kt < 32; ++kt){
      const int kc = kt*32 + lq*8;
      bf8 a0 = ldb(&As[ln*APS + kc]);
      bf8 a1 = ldb(&As[(16 + ln)*APS + kc]);
      #pragma unroll
      for (int nt = 0; nt < 2; ++nt){
        const int col = w*32 + nt*16 + ln;
        bf8 b = ldb(&fc1w[(size_t)col*1024 + kc]);
        acc[0][nt] = mfma(a0, b, acc[0][nt]);
        acc[1][nt] = mfma(a1, b, acc[1][nt]);
      }
    }
    #pragma unroll
    for (int nt = 0; nt < 2; ++nt){
      const int col = w*32 + nt*16 + ln;
      const float sc = sc2[col], sh = sh2[col];
      #pragma unroll
      for (int mt = 0; mt < 2; ++mt)
        #pragma unroll
        for (int e = 0; e < 4; ++e){
          float v = fmaxf(acc[mt][nt][e]*sc + sh, 0.f);
          actS[(mt*16 + lq*4 + e)*264 + col] = f2bf(v);
        }
    }
    __syncthreads();
  }

  if (w == 0){
    f4 acc[2] = {};
    for (int kt = 0; kt < 8; ++kt){
      const int kc = kt*32 + lq*8;
      bf8 a0 = ldb(&actS[ln*264 + kc]);
      bf8 a1 = ldb(&actS[(16 + ln)*264 + kc]);
      bf8 b  = ldb(&fc2wp[ln*256 + kc]);
      acc[0] = mfma(a0, b, acc[0]);
      acc[1] = mfma(a1, b, acc[1]);
    }
    const float bb = fc2b[ln];
    #pragma unroll
    for (int mt = 0; mt < 2; ++mt)
      #pragma unroll
      for (int e = 0; e < 4; ++e)
        lg[(mt*16 + lq*4 + e)*16 + ln] = acc[mt][e] + bb;
  }
  __syncthreads();
  if (tid < 32){
    const int r = tid;
    float mx = -1e30f;
    for (int cc = 0; cc < 10; ++cc) mx = fmaxf(mx, lg[r*16 + cc]);
    float sum = 0.f;
    for (int cc = 0; cc < 10; ++cc) sum += __expf(lg[r*16 + cc] - mx);
    const float lse = mx + logf(sum);
    for (int cc = 0; cc < 10; ++cc)
      out[(row0 + r)*10 + cc] = lg[r*16 + cc] - lse;
  }
}

// ---------------- launch ----------------
extern "C" void kernel_launch(void* const* d_in, const int* in_sizes, int n_in,
                              void* d_out, int out_size, void* d_ws, size_t ws_size,
                              hipStream_t stream)
{
  (void)in_sizes; (void)n_in; (void)out_size; (void)ws_size;
  char* ws = (char*)d_ws;
  auto US = [&](size_t off){ return (us*)(ws + off); };
  auto FP = [&](size_t off){ return (float*)(ws + off); };

  const float* x      = (const float*)d_in[0];
  const float* Wih0   = (const float*)d_in[1];
  const float* Whh0   = (const float*)d_in[2];
  const float* bih0   = (const float*)d_in[3];
  const float* bhh0   = (const float*)d_in[4];
  const float* Wih0r  = (const float*)d_in[5];
  const float* Whh0r  = (const float*)d_in[6];
  const float* bih0r  = (const float*)d_in[7];
  const float* bhh0r  = (const float*)d_in[8];
  const float* Wih1   = (const float*)d_in[9];
  const float* Whh1   = (const float*)d_in[10];
  const float* bih1   = (const float*)d_in[11];
  const float* bhh1   = (const float*)d_in[12];
  const float* Wih1r  = (const float*)d_in[13];
  // d_in[14] (W_hh_l1r) unused: backward layer-1 runs exactly one step from h=0.
  const float* bih1r  = (const float*)d_in[15];
  const float* bhh1r  = (const float*)d_in[16];
  const float* fc1w   = (const float*)d_in[17];
  const float* fc1b   = (const float*)d_in[18];
  const float* gma    = (const float*)d_in[19];
  const float* bta    = (const float*)d_in[20];
  const float* mean   = (const float*)d_in[21];
  const float* var    = (const float*)d_in[22];
  const float* fc2w   = (const float*)d_in[23];
  const float* fc2b   = (const float*)d_in[24];

  prep_kernel<<<512, 256, 0, stream>>>(
    Wih0, Whh0, bih0, bhh0, Wih0r, Whh0r, bih0r, bhh0r,
    Wih1, Whh1, bih1, bhh1, Wih1r, bih1r, bhh1r,
    fc1w, fc1b, gma, bta, mean, var, fc2w, fc2b,
    US(OFF_WCAT0), US(OFF_WCAT1), US(OFF_W1R), US(OFF_FC1W), US(OFF_FC2W),
    FP(OFF_BRZ0), FP(OFF_BNIH0), FP(OFF_BNHH0),
    FP(OFF_BRZ1), FP(OFF_BNIH1), FP(OFF_BNHH1),
    FP(OFF_BRZ1R), FP(OFF_BNIH1R), FP(OFF_BNHH1R),
    FP(OFF_SC2), FP(OFF_SH2), FP(OFF_FC2B));

  us* y0b  = US(OFF_Y0B);
  us* h0bf = US(OFF_H0BF);
  us* h1bf = US(OFF_H1BF);

  // ---- phase A: layer-0 backward (materialize y0b) ----
  for (int s = 0; s < 28; ++s){
    const int t = 27 - s;
    gru_step_kernel<<<256, 512, 0, stream>>>(
      x + t*28, 784, nullptr, 0, 32, nullptr, 0, 0,
      h0bf + (s & 1)*PP, FP(OFF_H0F32), h0bf + ((s & 1) ^ 1)*PP,
      y0b + t*512, 28ll*512,
      US(OFF_WCAT0) + 1536ll*544, 544, 17, 1, s == 0,
      FP(OFF_BRZ0) + 1024, FP(OFF_BNIH0) + 512, FP(OFF_BNHH0) + 512);
  }

  // ---- phase B: layer-0 forward + layer-1 forward interleaved ----
  for (int s = 0; s < 28; ++s){
    gru_step_kernel<<<256, 512, 0, stream>>>(
      x + s*28, 784, nullptr, 0, 32, nullptr, 0, 0,
      h0bf + (s & 1)*PP, FP(OFF_H0F32), h0bf + ((s & 1) ^ 1)*PP,
      nullptr, 0,
      US(OFF_WCAT0), 544, 17, 1, s == 0,
      FP(OFF_BRZ0), FP(OFF_BNIH0), FP(OFF_BNHH0));

    gru_step_kernel<<<256, 512, 0, stream>>>(
      nullptr, 0,
      h0bf + ((s & 1) ^ 1)*PP, 512, 512,      // y0f slice = h0f output of this step
      y0b + s*512, 28ll*512, 512,             // y0b slice
      h1bf + (s & 1)*PP, FP(OFF_H1F32), h1bf + ((s & 1) ^ 1)*PP,
      nullptr, 0,
      US(OFF_WCAT1), 1536, 48, 32, s == 0,
      FP(OFF_BRZ1), FP(OFF_BNIH1), FP(OFF_BNHH1));
  }

  // ---- layer-1 backward: single step from h=0 on [y0f(27)|y0b(27)] ----
  gru_step_kernel<<<256, 512, 0, stream>>>(
    nullptr, 0,
    h0bf + 0*PP, 512, 512,                    // y0f t=27 slice (l0f(27) wrote pp buffer 0)
    y0b + 27*512, 28ll*512, 512,
    h1bf, FP(OFF_H1F32), US(OFF_H1BBF),
    nullptr, 0,
    US(OFF_W1R), 1024, 32, 32, 1,
    FP(OFF_BRZ1R), FP(OFF_BNIH1R), FP(OFF_BNHH1R));

  // ---- head (final h1f is pp buffer 0 after 28 steps) ----
  head_kernel<<<128, 512, 0, stream>>>(
    h1bf, US(OFF_H1BBF), US(OFF_FC1W), US(OFF_FC2W),
    FP(OFF_SC2), FP(OFF_SH2), FP(OFF_FC2B), (float*)d_out);
}